// Round 1
// baseline (360.061 us; speedup 1.0000x reference)
//
#include <hip/hip_runtime.h>
#include <stdint.h>

// ---------------------------------------------------------------------------
// AbstractAttention: out = AttnLayer(q_in,k_in,v_in; W_Q,W_K,W_V,W_O,biases)
// B=2, S=2048, H=16, Dh=64, Dm=1024.  fp32 in/out, bf16 MFMA internally.
//
// ws layout (elements of u16/bf16):
//   xq/xk/xv bf16    : 3 * 4194304
//   WqT/WkT/WvT/WoT  : 4 * 1048576   (B^T layout [n][k])
//   q [b,h,s,e]      : 4194304       (bias + 1/8 scale folded in)
//   k [b,h,s,e]      : 4194304
//   vT [b,h,e,s]     : 4194304
//   z [b,s,h,e]      : 4194304
// total 64 MB.
// ---------------------------------------------------------------------------

typedef __attribute__((ext_vector_type(8))) short short8;
typedef __attribute__((ext_vector_type(4))) float floatx4;

#define MFMA16(a, b, c) __builtin_amdgcn_mfma_f32_16x16x32_bf16(a, b, c, 0, 0, 0)

__device__ __forceinline__ unsigned short f2b(float f) {
  // RNE float->bf16 (inputs finite; no NaN path needed)
  unsigned int u = __builtin_bit_cast(unsigned int, f);
  u = (u + 0x7fffu + ((u >> 16) & 1u)) >> 16;
  return (unsigned short)u;
}

__device__ __forceinline__ void async_copy16(void* lds, const void* g) {
  // wave-uniform LDS base + lane*16B (HW semantics); per-lane global gather
  __builtin_amdgcn_global_load_lds(
      (const __attribute__((address_space(1))) unsigned int*)g,
      (__attribute__((address_space(3))) unsigned int*)lds, 16, 0, 0);
}

// ---------------------------------------------------------------------------
// Conversions
// ---------------------------------------------------------------------------
__global__ __launch_bounds__(256) void conv_x3(const float* __restrict__ a,
                                               const float* __restrict__ b,
                                               const float* __restrict__ c,
                                               unsigned short* __restrict__ out) {
  const float* in = (blockIdx.y == 0) ? a : ((blockIdx.y == 1) ? b : c);
  size_t i = (size_t)blockIdx.x * 256 + threadIdx.x;  // i indexes float4 groups
  float4 v = ((const float4*)in)[i];
  ushort4 u;
  u.x = f2b(v.x); u.y = f2b(v.y); u.z = f2b(v.z); u.w = f2b(v.w);
  ((ushort4*)(out + (size_t)blockIdx.y * 4194304))[i] = u;
}

// W_Q/W_K/W_V [h,d,e] -> Wt [n=h*64+e][k=d]  (B^T layout)
__global__ __launch_bounds__(256) void conv_w3(const float* __restrict__ a,
                                               const float* __restrict__ b,
                                               const float* __restrict__ c,
                                               unsigned short* __restrict__ out) {
  const float* in = (blockIdx.y == 0) ? a : ((blockIdx.y == 1) ? b : c);
  int o = blockIdx.x * 256 + threadIdx.x;   // 0..1048575
  int he = o >> 10, d = o & 1023;
  float v = in[((he >> 6) << 16) + (d << 6) + (he & 63)];
  out[(size_t)blockIdx.y * 1048576 + o] = f2b(v);
}

// W_O [he,d] -> WoT [n=d][k=he]
__global__ __launch_bounds__(256) void conv_wo(const float* __restrict__ in,
                                               unsigned short* __restrict__ out) {
  int o = blockIdx.x * 256 + threadIdx.x;
  int d = o >> 10, he = o & 1023;
  out[o] = f2b(in[(he << 10) + d]);
}

// ---------------------------------------------------------------------------
// GEMM: C[M=4096][N=1024] = A[4096][1024] * Bt[1024][1024]^T (+bias)*scale
// 64x64 tile / block, 4 waves, wave = 32x32 (2x2 of 16x16x32 MFMA).
// mode 0: fp32 plain [m][n] -> outf  (final projection, scale unused=1)
// mode 1: bf16 -> [b,h,s,e]          (q with scale=0.125, k with scale=1)
// mode 2: bf16 -> [b,h,e,s]          (v transposed)
// ---------------------------------------------------------------------------
__global__ __launch_bounds__(256) void gemm_qkvo(
    const short* __restrict__ A, const short* __restrict__ Bt,
    const float* __restrict__ bias, unsigned short* __restrict__ outb,
    float* __restrict__ outf, int mode, float scale) {
  __shared__ short As[64 * 32];
  __shared__ short Bs[64 * 32];

  const int tid = threadIdx.x;
  const int lane = tid & 63, w = tid >> 6;
  const int quad = lane >> 4, col = lane & 15;
  const int m0 = blockIdx.y * 64, n0 = blockIdx.x * 64;

  floatx4 acc00 = {0.f, 0.f, 0.f, 0.f}, acc01 = {0.f, 0.f, 0.f, 0.f};
  floatx4 acc10 = {0.f, 0.f, 0.f, 0.f}, acc11 = {0.f, 0.f, 0.f, 0.f};
  const int lr0 = (w >> 1) * 32, lc0 = (w & 1) * 32;

  const short* ga = A + (size_t)(m0 + w * 16 + (lane >> 2)) * 1024 + (lane & 3) * 8;
  const short* gb = Bt + (size_t)(n0 + w * 16 + (lane >> 2)) * 1024 + (lane & 3) * 8;
  short* la = &As[w * 512];
  short* lb = &Bs[w * 512];

  for (int k0 = 0; k0 < 1024; k0 += 32) {
    async_copy16(la, ga + k0);
    async_copy16(lb, gb + k0);
    __syncthreads();
    short8 a0 = *(const short8*)&As[(lr0 + col) * 32 + quad * 8];
    short8 a1 = *(const short8*)&As[(lr0 + 16 + col) * 32 + quad * 8];
    short8 b0 = *(const short8*)&Bs[(lc0 + col) * 32 + quad * 8];
    short8 b1 = *(const short8*)&Bs[(lc0 + 16 + col) * 32 + quad * 8];
    acc00 = MFMA16(a0, b0, acc00);
    acc01 = MFMA16(a0, b1, acc01);
    acc10 = MFMA16(a1, b0, acc10);
    acc11 = MFMA16(a1, b1, acc11);
    __syncthreads();
  }

  floatx4 acc[2][2] = {{acc00, acc01}, {acc10, acc11}};
  const int mb = m0 + lr0, nb = n0 + lc0;
#pragma unroll
  for (int i = 0; i < 2; ++i)
#pragma unroll
    for (int j = 0; j < 2; ++j)
#pragma unroll
      for (int r = 0; r < 4; ++r) {
        int m = mb + i * 16 + quad * 4 + r;
        int n = nb + j * 16 + col;
        float v = acc[i][j][r] + bias[n];
        if (mode == 0) {
          outf[(size_t)m * 1024 + n] = v;
        } else {
          v *= scale;
          unsigned short hv = f2b(v);
          int bb = m >> 11, s = m & 2047, h = n >> 6, e = n & 63;
          size_t addr;
          if (mode == 1)
            addr = (((size_t)bb * 16 + h) * 2048 + s) * 64 + e;
          else
            addr = (((size_t)bb * 16 + h) * 64 + e) * 2048 + s;
          outb[addr] = hv;
        }
      }
}

// ---------------------------------------------------------------------------
// Flash attention (causal). block = (b,h, 64-row q tile), 4 waves x 16 rows.
// q,k: [b,h,s,e] bf16 (q pre-scaled by 1/8, bias folded).  vt: [b,h,e,s].
// z out: [b,s,h,e] bf16.
// ---------------------------------------------------------------------------
__global__ __launch_bounds__(256) void attn(const short* __restrict__ q,
                                            const short* __restrict__ k,
                                            const short* __restrict__ vt,
                                            unsigned short* __restrict__ z) {
  __shared__ short Ks[64 * 64];      // [key][e]
  __shared__ short Vs[64 * 64];      // [e][key]
  __shared__ short Ps[4][16 * 64];   // per-wave P transpose staging

  const int tid = threadIdx.x;
  const int lane = tid & 63, w = tid >> 6;
  const int quad = lane >> 4, col = lane & 15;
  const int qt = blockIdx.x & 31, bh = blockIdx.x >> 5;
  const int q0 = qt * 64, qw0 = q0 + w * 16;
  const size_t base = (size_t)bh * 2048 * 64;

  // Q fragments (held in registers for whole kernel)
  const short* qp = q + base + (size_t)(qw0 + col) * 64 + quad * 8;
  short8 aq0 = *(const short8*)qp;
  short8 aq1 = *(const short8*)(qp + 32);

  floatx4 o[4] = {{0.f, 0.f, 0.f, 0.f}, {0.f, 0.f, 0.f, 0.f},
                  {0.f, 0.f, 0.f, 0.f}, {0.f, 0.f, 0.f, 0.f}};
  float m_run[4], l_run[4];
#pragma unroll
  for (int r = 0; r < 4; ++r) { m_run[r] = -1e30f; l_run[r] = 0.f; }

  const short* kg = k + base;
  const short* vg = vt + base;

  for (int t = 0; t <= qt; ++t) {
    const int kv0 = t * 64;
    {
      const short* kr = kg + (size_t)(kv0 + w * 16 + (lane >> 3)) * 64 + (lane & 7) * 8;
      async_copy16(&Ks[(w * 16) * 64], kr);
      async_copy16(&Ks[(w * 16 + 8) * 64], kr + 8 * 64);
      const short* vr = vg + (size_t)(w * 16 + (lane >> 3)) * 2048 + kv0 + (lane & 7) * 8;
      async_copy16(&Vs[(w * 16) * 64], vr);
      async_copy16(&Vs[(w * 16 + 8) * 64], vr + 8 * 2048);
    }
    __syncthreads();

    // S = Q K^T  (wave's 16 q-rows x 64 keys)
    floatx4 s[4];
#pragma unroll
    for (int nt = 0; nt < 4; ++nt) {
      const short* kbp = &Ks[(nt * 16 + col) * 64 + quad * 8];
      short8 bk0 = *(const short8*)kbp;
      short8 bk1 = *(const short8*)(kbp + 32);
      floatx4 a = {0.f, 0.f, 0.f, 0.f};
      a = MFMA16(aq0, bk0, a);
      a = MFMA16(aq1, bk1, a);
      s[nt] = a;
    }

    // causal mask + row max
    float rmax[4] = {-1e30f, -1e30f, -1e30f, -1e30f};
#pragma unroll
    for (int nt = 0; nt < 4; ++nt) {
      int key = kv0 + nt * 16 + col;
#pragma unroll
      for (int r = 0; r < 4; ++r) {
        int qrow = qw0 + quad * 4 + r;
        float v = (key <= qrow) ? s[nt][r] : -1e9f;
        s[nt][r] = v;
        rmax[r] = fmaxf(rmax[r], v);
      }
    }
#pragma unroll
    for (int off = 1; off < 16; off <<= 1)
#pragma unroll
      for (int r = 0; r < 4; ++r)
        rmax[r] = fmaxf(rmax[r], __shfl_xor(rmax[r], off, 64));

    float alpha[4], rsum[4];
#pragma unroll
    for (int r = 0; r < 4; ++r) {
      float mnew = fmaxf(m_run[r], rmax[r]);
      alpha[r] = __expf(m_run[r] - mnew);
      m_run[r] = mnew;
      rsum[r] = 0.f;
    }

    // P = exp(S - m), write C-layout -> LDS (wave-private; same-wave DS order)
    short* pw = &Ps[w][0];
#pragma unroll
    for (int nt = 0; nt < 4; ++nt)
#pragma unroll
      for (int r = 0; r < 4; ++r) {
        float p = __expf(s[nt][r] - m_run[r]);
        rsum[r] += p;
        pw[(quad * 4 + r) * 64 + nt * 16 + col] = (short)f2b(p);
      }
#pragma unroll
    for (int off = 1; off < 16; off <<= 1)
#pragma unroll
      for (int r = 0; r < 4; ++r) rsum[r] += __shfl_xor(rsum[r], off, 64);
#pragma unroll
    for (int r = 0; r < 4; ++r) l_run[r] = l_run[r] * alpha[r] + rsum[r];

    // rescale O, read P back as A-operand, accumulate PV
#pragma unroll
    for (int et = 0; et < 4; ++et)
#pragma unroll
      for (int r = 0; r < 4; ++r) o[et][r] *= alpha[r];

    short8 ap0 = *(const short8*)&pw[col * 64 + quad * 8];
    short8 ap1 = *(const short8*)&pw[col * 64 + 32 + quad * 8];
#pragma unroll
    for (int et = 0; et < 4; ++et) {
      const short* vb = &Vs[(et * 16 + col) * 64 + quad * 8];
      short8 bv0 = *(const short8*)vb;
      short8 bv1 = *(const short8*)(vb + 32);
      o[et] = MFMA16(ap0, bv0, o[et]);
      o[et] = MFMA16(ap1, bv1, o[et]);
    }
    __syncthreads();
  }

  // epilogue: z[b,s,h,e] = O / l
  const int b = bh >> 4, h = bh & 15;
#pragma unroll
  for (int et = 0; et < 4; ++et)
#pragma unroll
    for (int r = 0; r < 4; ++r) {
      float val = o[et][r] / l_run[r];
      int sq = qw0 + quad * 4 + r;
      int e = et * 16 + col;
      z[(((size_t)b * 2048 + sq) * 16 + h) * 64 + e] = f2b(val);
    }
}

// ---------------------------------------------------------------------------
extern "C" void kernel_launch(void* const* d_in, const int* in_sizes, int n_in,
                              void* d_out, int out_size, void* d_ws, size_t ws_size,
                              hipStream_t stream) {
  (void)in_sizes; (void)n_in; (void)out_size; (void)ws_size;
  const float* Xq = (const float*)d_in[0];
  const float* Xk = (const float*)d_in[1];
  const float* Xv = (const float*)d_in[2];
  const float* WQ = (const float*)d_in[3];
  const float* WK = (const float*)d_in[4];
  const float* WV = (const float*)d_in[5];
  const float* WO = (const float*)d_in[6];
  const float* bQ = (const float*)d_in[7];
  const float* bK = (const float*)d_in[8];
  const float* bV = (const float*)d_in[9];
  const float* bO = (const float*)d_in[10];
  float* out = (float*)d_out;

  unsigned short* xqb = (unsigned short*)d_ws;   // needs 64 MB of ws
  unsigned short* xkb = xqb + 4194304;
  unsigned short* xvb = xkb + 4194304;
  unsigned short* wqt = xvb + 4194304;
  unsigned short* wkt = wqt + 1048576;
  unsigned short* wvt = wkt + 1048576;
  unsigned short* wot = wvt + 1048576;
  unsigned short* qb = wot + 1048576;
  unsigned short* kb = qb + 4194304;
  unsigned short* vtb = kb + 4194304;
  unsigned short* zb = vtb + 4194304;

  conv_x3<<<dim3(4096, 3), 256, 0, stream>>>(Xq, Xk, Xv, xqb);
  conv_w3<<<dim3(4096, 3), 256, 0, stream>>>(WQ, WK, WV, wqt);
  conv_wo<<<4096, 256, 0, stream>>>(WO, wot);

  dim3 gg(16, 64);
  gemm_qkvo<<<gg, 256, 0, stream>>>((const short*)xqb, (const short*)wqt, bQ,
                                    qb, nullptr, 1, 0.125f);
  gemm_qkvo<<<gg, 256, 0, stream>>>((const short*)xkb, (const short*)wkt, bK,
                                    kb, nullptr, 1, 1.0f);
  gemm_qkvo<<<gg, 256, 0, stream>>>((const short*)xvb, (const short*)wvt, bV,
                                    vtb, nullptr, 2, 1.0f);
  attn<<<1024, 256, 0, stream>>>((const short*)qb, (const short*)kb,
                                 (const short*)vtb, zb);
  gemm_qkvo<<<gg, 256, 0, stream>>>((const short*)zb, (const short*)wot, bO,
                                    nullptr, out, 0, 1.0f);
}

// Round 2
// 247.968 us; speedup vs baseline: 1.4520x; 1.4520x over previous
//
#include <hip/hip_runtime.h>
#include <stdint.h>

// ---------------------------------------------------------------------------
// AbstractAttention  B=2,S=2048,H=16,Dh=64,Dm=1024. fp32 in/out, bf16 MFMA.
// R2: XOR-swizzled LDS (kills 16-way bank conflicts), S^T attention
// formulation (P transposed by construction, bpermute exchange instead of
// LDS round-trip), exp2 softmax, LDS-transpose weight conversions.
// ---------------------------------------------------------------------------

typedef __attribute__((ext_vector_type(8))) short short8;
typedef __attribute__((ext_vector_type(4))) float floatx4;
typedef __attribute__((ext_vector_type(4))) unsigned int uintx4;

#define MFMA16(a, b, c) __builtin_amdgcn_mfma_f32_16x16x32_bf16(a, b, c, 0, 0, 0)

__device__ __forceinline__ unsigned short f2b(float f) {  // RNE fp32->bf16
  unsigned int u = __builtin_bit_cast(unsigned int, f);
  u = (u + 0x7fffu + ((u >> 16) & 1u)) >> 16;
  return (unsigned short)u;
}
__device__ __forceinline__ float exp2f_fast(float x) {
#if __has_builtin(__builtin_amdgcn_exp2f)
  return __builtin_amdgcn_exp2f(x);
#else
  return exp2f(x);
#endif
}
// pack two fp32 -> packed bf16x2 (truncation; 1 v_perm)
__device__ __forceinline__ unsigned int pack2_bf16(float lo, float hi) {
#if __has_builtin(__builtin_amdgcn_perm)
  return __builtin_amdgcn_perm(__builtin_bit_cast(unsigned int, hi),
                               __builtin_bit_cast(unsigned int, lo), 0x07060302u);
#else
  return (__builtin_bit_cast(unsigned int, lo) >> 16) |
         (__builtin_bit_cast(unsigned int, hi) & 0xffff0000u);
#endif
}

__device__ __forceinline__ void async_copy16(void* lds, const void* g) {
  __builtin_amdgcn_global_load_lds(
      (const __attribute__((address_space(1))) unsigned int*)g,
      (__attribute__((address_space(3))) unsigned int*)lds, 16, 0, 0);
}

// ---------------------------------------------------------------------------
// Conversions
// ---------------------------------------------------------------------------
__global__ __launch_bounds__(256) void conv_x3(const float* __restrict__ a,
                                               const float* __restrict__ b,
                                               const float* __restrict__ c,
                                               unsigned short* __restrict__ out) {
  const float* in = (blockIdx.y == 0) ? a : ((blockIdx.y == 1) ? b : c);
  size_t i = (size_t)blockIdx.x * 256 + threadIdx.x;
  float4 v = ((const float4*)in)[i];
  ushort4 u;
  u.x = f2b(v.x); u.y = f2b(v.y); u.z = f2b(v.z); u.w = f2b(v.w);
  ((ushort4*)(out + (size_t)blockIdx.y * 4194304))[i] = u;
}

// W_{Q,K,V} [h,d,e] fp32 -> Wt [n=h*64+e][k=d] bf16 (coalesced LDS transpose)
__global__ __launch_bounds__(256) void conv_w3(const float* __restrict__ a,
                                               const float* __restrict__ b,
                                               const float* __restrict__ c,
                                               unsigned short* __restrict__ out) {
  __shared__ float T[64][65];
  const float* in = (blockIdx.y == 0) ? a : ((blockIdx.y == 1) ? b : c);
  const int t = threadIdx.x, rr = t >> 4, cc = t & 15;
  const int h = blockIdx.x >> 4, d0 = (blockIdx.x & 15) << 6;
#pragma unroll
  for (int it = 0; it < 4; ++it) {
    int dl = it * 16 + rr;
    float4 v = *(const float4*)&in[(size_t)h * 65536 + (size_t)(d0 + dl) * 64 + cc * 4];
    T[dl][cc * 4 + 0] = v.x; T[dl][cc * 4 + 1] = v.y;
    T[dl][cc * 4 + 2] = v.z; T[dl][cc * 4 + 3] = v.w;
  }
  __syncthreads();
  unsigned short* ob = out + (size_t)blockIdx.y * 1048576;
#pragma unroll
  for (int it = 0; it < 4; ++it) {
    int e = it * 16 + rr;
    ushort4 u;
    u.x = f2b(T[cc * 4 + 0][e]); u.y = f2b(T[cc * 4 + 1][e]);
    u.z = f2b(T[cc * 4 + 2][e]); u.w = f2b(T[cc * 4 + 3][e]);
    *(ushort4*)&ob[(size_t)(h * 64 + e) * 1024 + d0 + cc * 4] = u;
  }
}

// W_O [he,d] fp32 -> WoT [n=d][k=he] bf16
__global__ __launch_bounds__(256) void conv_wo(const float* __restrict__ in,
                                               unsigned short* __restrict__ out) {
  __shared__ float T[64][65];
  const int t = threadIdx.x, rr = t >> 4, cc = t & 15;
  const int r0 = (blockIdx.x & 15) << 6;  // he block
  const int c0 = (blockIdx.x >> 4) << 6;  // d block
#pragma unroll
  for (int it = 0; it < 4; ++it) {
    int rl = it * 16 + rr;
    float4 v = *(const float4*)&in[(size_t)(r0 + rl) * 1024 + c0 + cc * 4];
    T[rl][cc * 4 + 0] = v.x; T[rl][cc * 4 + 1] = v.y;
    T[rl][cc * 4 + 2] = v.z; T[rl][cc * 4 + 3] = v.w;
  }
  __syncthreads();
#pragma unroll
  for (int it = 0; it < 4; ++it) {
    int dl = it * 16 + rr;
    ushort4 u;
    u.x = f2b(T[cc * 4 + 0][dl]); u.y = f2b(T[cc * 4 + 1][dl]);
    u.z = f2b(T[cc * 4 + 2][dl]); u.w = f2b(T[cc * 4 + 3][dl]);
    *(ushort4*)&out[(size_t)(c0 + dl) * 1024 + r0 + cc * 4] = u;
  }
}

// ---------------------------------------------------------------------------
// GEMM: C[4096][1024] = A * Bt^T (+bias)*scale; 64x64 tile, XOR-swizzled LDS.
// mode 0: fp32 [m][n]; mode 1: bf16 [b,h,s,e]; mode 2: bf16 [b,h,e,s]
// ---------------------------------------------------------------------------
__global__ __launch_bounds__(256) void gemm_qkvo(
    const short* __restrict__ A, const short* __restrict__ Bt,
    const float* __restrict__ bias, unsigned short* __restrict__ outb,
    float* __restrict__ outf, int mode, float scale) {
  __shared__ short As[64 * 32];
  __shared__ short Bs[64 * 32];

  const int tid = threadIdx.x;
  const int lane = tid & 63, w = tid >> 6;
  const int quad = lane >> 4, col = lane & 15;
  const int m0 = blockIdx.y * 64, n0 = blockIdx.x * 64;

  floatx4 acc00 = {0.f, 0.f, 0.f, 0.f}, acc01 = {0.f, 0.f, 0.f, 0.f};
  floatx4 acc10 = {0.f, 0.f, 0.f, 0.f}, acc11 = {0.f, 0.f, 0.f, 0.f};
  const int lr0 = (w >> 1) * 32, lc0 = (w & 1) * 32;

  // staging: lane -> row lane>>2, physical chunk lane&3 holds logical chunk
  // (lane&3)^f(row), f(row)=(row>>1)&3  (spreads quarter-wave over 8 bank grps)
  const int lr = lane >> 2, gc = (lane & 3) ^ ((lane >> 3) & 3);
  const short* ga = A + (size_t)(m0 + w * 16 + lr) * 1024 + gc * 8;
  const short* gb = Bt + (size_t)(n0 + w * 16 + lr) * 1024 + gc * 8;
  short* la = &As[w * 512];
  short* lb = &Bs[w * 512];
  const int asw = (col >> 1) & 3;  // f(row) for frag reads (rows = lr0{+16}+col)

  for (int k0 = 0; k0 < 1024; k0 += 32) {
    async_copy16(la, ga + k0);
    async_copy16(lb, gb + k0);
    __syncthreads();
    short8 a0 = *(const short8*)&As[(lr0 + col) * 32 + (quad ^ asw) * 8];
    short8 a1 = *(const short8*)&As[(lr0 + 16 + col) * 32 + (quad ^ asw) * 8];
    short8 b0 = *(const short8*)&Bs[(lc0 + col) * 32 + (quad ^ asw) * 8];
    short8 b1 = *(const short8*)&Bs[(lc0 + 16 + col) * 32 + (quad ^ asw) * 8];
    acc00 = MFMA16(a0, b0, acc00);
    acc01 = MFMA16(a0, b1, acc01);
    acc10 = MFMA16(a1, b0, acc10);
    acc11 = MFMA16(a1, b1, acc11);
    __syncthreads();
  }

  floatx4 acc[2][2] = {{acc00, acc01}, {acc10, acc11}};
  const int mb = m0 + lr0, nb = n0 + lc0;
#pragma unroll
  for (int i = 0; i < 2; ++i)
#pragma unroll
    for (int j = 0; j < 2; ++j)
#pragma unroll
      for (int r = 0; r < 4; ++r) {
        int m = mb + i * 16 + quad * 4 + r;
        int n = nb + j * 16 + col;
        float v = acc[i][j][r] + bias[n];
        if (mode == 0) {
          outf[(size_t)m * 1024 + n] = v;
        } else {
          v *= scale;
          unsigned short hv = f2b(v);
          int bb = m >> 11, s = m & 2047, h = n >> 6, e = n & 63;
          size_t addr;
          if (mode == 1)
            addr = (((size_t)bb * 16 + h) * 2048 + s) * 64 + e;
          else
            addr = (((size_t)bb * 16 + h) * 64 + e) * 2048 + s;
          outb[addr] = hv;
        }
      }
}

// ---------------------------------------------------------------------------
// Flash attention (causal), S^T formulation.
// q,k: [b,h,s,e] bf16 (q pre-scaled by log2e/8), vt: [b,h,e,s], z: [b,s,h,e].
// Per block: one 64-row q tile of one (b,h); 4 waves x 16 q.
// S^T = K*Q^T (keys=M, q=N) -> P^T in C-layout -> O^T = V^T * P^T.
// P^T C-layout -> B-operand needs only a quad exchange: 16 bpermute + selects.
// ---------------------------------------------------------------------------
__global__ __launch_bounds__(256) void attn(const short* __restrict__ q,
                                            const short* __restrict__ k,
                                            const short* __restrict__ vt,
                                            unsigned short* __restrict__ z) {
  __shared__ short Ks[64 * 64];  // [key][e], 16B chunks XOR-swizzled by row&7
  __shared__ short Vs[64 * 64];  // [e][key], same swizzle

  const int tid = threadIdx.x;
  const int lane = tid & 63, w = tid >> 6;
  const int quad = lane >> 4, col = lane & 15;
  const int qt = 31 - (blockIdx.x >> 5), bh = blockIdx.x & 31;  // long blocks first
  const int q0 = qt * 64, qw0 = q0 + w * 16;
  const size_t base = (size_t)bh * (2048 * 64);

  // Q B-fragments: B[n=col][k=quad*8+j], two K=32 halves
  const short* qp = q + base + (size_t)(qw0 + col) * 64 + quad * 8;
  short8 bq0 = *(const short8*)qp;
  short8 bq1 = *(const short8*)(qp + 32);

  floatx4 o[4] = {{0.f,0.f,0.f,0.f},{0.f,0.f,0.f,0.f},{0.f,0.f,0.f,0.f},{0.f,0.f,0.f,0.f}};
  float m_run = -1e30f, l_run = 0.f;  // per q=col (base-2 domain)

  const short* kg = k + base;
  const short* vg = vt + base;
  const int ksw = col & 7;               // row&7 for frag reads
  const int slr = lane >> 3, slc = lane & 7;
  const int sgc = slc ^ slr;             // staging: swizzled global chunk
  const int srcA = ((quad & 1) << 5) + col, srcB = srcA + 16;
  const bool hiq = (quad & 2) != 0;

  for (int t = 0; t <= qt; ++t) {
    const int kv0 = t * 64;
    {
      const short* kr = kg + (size_t)(kv0 + w * 16 + slr) * 64 + sgc * 8;
      async_copy16(&Ks[(w * 16) * 64], kr);
      async_copy16(&Ks[(w * 16 + 8) * 64], kr + 8 * 64);
      const short* vr = vg + (size_t)(w * 16 + slr) * 2048 + kv0 + sgc * 8;
      async_copy16(&Vs[(w * 16) * 64], vr);
      async_copy16(&Vs[(w * 16 + 8) * 64], vr + 8 * 2048);
    }
    __syncthreads();

    const bool diag = (t == qt);
    const int mtmax = diag ? w : 3;  // wave-uniform

    // S^T[key][q]: 4 key-subtiles of 16
    floatx4 st[4];
#pragma unroll
    for (int mt = 0; mt < 4; ++mt) {
      if (mt <= mtmax) {
        const short* kb = &Ks[(mt * 16 + col) * 64];
        short8 ka0 = *(const short8*)(kb + (quad ^ ksw) * 8);
        short8 ka1 = *(const short8*)(kb + ((quad + 4) ^ ksw) * 8);
        floatx4 a = {0.f, 0.f, 0.f, 0.f};
        a = MFMA16(ka0, bq0, a);
        a = MFMA16(ka1, bq1, a);
        if (diag && mt == mtmax) {  // diagonal subtile: elementwise causal mask
#pragma unroll
          for (int r = 0; r < 4; ++r)
            if (quad * 4 + r > col) a[r] = -1e9f;
        }
        st[mt] = a;
      }
    }

    // per-lane partial max over keys, then reduce across the 4 quads
    float pmax = -1e30f;
#pragma unroll
    for (int mt = 0; mt < 4; ++mt)
      if (mt <= mtmax) {
#pragma unroll
        for (int r = 0; r < 4; ++r) pmax = fmaxf(pmax, st[mt][r]);
      }
    pmax = fmaxf(pmax, __shfl_xor(pmax, 16, 64));
    pmax = fmaxf(pmax, __shfl_xor(pmax, 32, 64));
    float mnew = fmaxf(m_run, pmax);
    float alpha = exp2f_fast(m_run - mnew);
    m_run = mnew;

    // P^T = exp2(S^T - m): pack to bf16 pairs (keys r0r1, r2r3 per subtile)
    unsigned int u01[4], u23[4];
    float lsum = 0.f;
#pragma unroll
    for (int mt = 0; mt < 4; ++mt) {
      if (mt <= mtmax) {
        float p0 = exp2f_fast(st[mt][0] - mnew);
        float p1 = exp2f_fast(st[mt][1] - mnew);
        float p2 = exp2f_fast(st[mt][2] - mnew);
        float p3 = exp2f_fast(st[mt][3] - mnew);
        lsum += (p0 + p1) + (p2 + p3);
        u01[mt] = pack2_bf16(p0, p1);
        u23[mt] = pack2_bf16(p2, p3);
      } else {
        u01[mt] = 0u; u23[mt] = 0u;
      }
    }
    lsum += __shfl_xor(lsum, 16, 64);
    lsum += __shfl_xor(lsum, 32, 64);
    l_run = l_run * alpha + lsum;

    // quad exchange: build P^T B-fragments (keys quad*8+j within each half)
    unsigned int xA0 = (unsigned int)__shfl((int)u01[0], srcA, 64);
    unsigned int xA1 = (unsigned int)__shfl((int)u01[1], srcA, 64);
    unsigned int yA0 = (unsigned int)__shfl((int)u23[0], srcA, 64);
    unsigned int yA1 = (unsigned int)__shfl((int)u23[1], srcA, 64);
    unsigned int xB0 = (unsigned int)__shfl((int)u01[0], srcB, 64);
    unsigned int xB1 = (unsigned int)__shfl((int)u01[1], srcB, 64);
    unsigned int yB0 = (unsigned int)__shfl((int)u23[0], srcB, 64);
    unsigned int yB1 = (unsigned int)__shfl((int)u23[1], srcB, 64);
    uintx4 v0;
    v0.x = hiq ? xA1 : xA0; v0.y = hiq ? yA1 : yA0;
    v0.z = hiq ? xB1 : xB0; v0.w = hiq ? yB1 : yB0;
    short8 pf0 = __builtin_bit_cast(short8, v0);
    xA0 = (unsigned int)__shfl((int)u01[2], srcA, 64);
    xA1 = (unsigned int)__shfl((int)u01[3], srcA, 64);
    yA0 = (unsigned int)__shfl((int)u23[2], srcA, 64);
    yA1 = (unsigned int)__shfl((int)u23[3], srcA, 64);
    xB0 = (unsigned int)__shfl((int)u01[2], srcB, 64);
    xB1 = (unsigned int)__shfl((int)u01[3], srcB, 64);
    yB0 = (unsigned int)__shfl((int)u23[2], srcB, 64);
    yB1 = (unsigned int)__shfl((int)u23[3], srcB, 64);
    uintx4 v1;
    v1.x = hiq ? xA1 : xA0; v1.y = hiq ? yA1 : yA0;
    v1.z = hiq ? xB1 : xB0; v1.w = hiq ? yB1 : yB0;
    short8 pf1 = __builtin_bit_cast(short8, v1);

    // O^T = V^T * P^T, with online rescale by alpha
#pragma unroll
    for (int et = 0; et < 4; ++et) {
      const short* vb = &Vs[(et * 16 + col) * 64];
      short8 va0 = *(const short8*)(vb + (quad ^ ksw) * 8);
      short8 va1 = *(const short8*)(vb + ((quad + 4) ^ ksw) * 8);
      floatx4 t0 = o[et];
#pragma unroll
      for (int r = 0; r < 4; ++r) t0[r] *= alpha;
      t0 = MFMA16(va0, pf0, t0);
      t0 = MFMA16(va1, pf1, t0);
      o[et] = t0;
    }
    __syncthreads();
  }

  // epilogue: z[b, s=qw0+col, h, e] = O^T[e][q]/l ; 8B packed stores
  const int b = bh >> 4, h = bh & 15;
#if __has_builtin(__builtin_amdgcn_rcpf)
  const float invl = __builtin_amdgcn_rcpf(l_run);
#else
  const float invl = 1.f / l_run;
#endif
  unsigned short* zr = z + (((size_t)b * 2048 + qw0 + col) * 16 + h) * 64;
#pragma unroll
  for (int et = 0; et < 4; ++et) {
    ushort4 u;
    u.x = f2b(o[et][0] * invl); u.y = f2b(o[et][1] * invl);
    u.z = f2b(o[et][2] * invl); u.w = f2b(o[et][3] * invl);
    *(ushort4*)&zr[et * 16 + quad * 4] = u;
  }
}

// ---------------------------------------------------------------------------
extern "C" void kernel_launch(void* const* d_in, const int* in_sizes, int n_in,
                              void* d_out, int out_size, void* d_ws, size_t ws_size,
                              hipStream_t stream) {
  (void)in_sizes; (void)n_in; (void)out_size; (void)ws_size;
  const float* Xq = (const float*)d_in[0];
  const float* Xk = (const float*)d_in[1];
  const float* Xv = (const float*)d_in[2];
  const float* WQ = (const float*)d_in[3];
  const float* WK = (const float*)d_in[4];
  const float* WV = (const float*)d_in[5];
  const float* WO = (const float*)d_in[6];
  const float* bQ = (const float*)d_in[7];
  const float* bK = (const float*)d_in[8];
  const float* bV = (const float*)d_in[9];
  const float* bO = (const float*)d_in[10];
  float* out = (float*)d_out;

  unsigned short* xqb = (unsigned short*)d_ws;
  unsigned short* xkb = xqb + 4194304;
  unsigned short* xvb = xkb + 4194304;
  unsigned short* wqt = xvb + 4194304;
  unsigned short* wkt = wqt + 1048576;
  unsigned short* wvt = wkt + 1048576;
  unsigned short* wot = wvt + 1048576;
  unsigned short* qb = wot + 1048576;
  unsigned short* kb = qb + 4194304;
  unsigned short* vtb = kb + 4194304;
  unsigned short* zb = vtb + 4194304;

  conv_x3<<<dim3(4096, 3), 256, 0, stream>>>(Xq, Xk, Xv, xqb);
  conv_w3<<<dim3(256, 3), 256, 0, stream>>>(WQ, WK, WV, wqt);
  conv_wo<<<256, 256, 0, stream>>>(WO, wot);

  dim3 gg(16, 64);
  // Q scale folds 1/sqrt(64) and log2(e) for the exp2 softmax domain
  const float qscale = 0.125f * 1.44269504088896f;
  gemm_qkvo<<<gg, 256, 0, stream>>>((const short*)xqb, (const short*)wqt, bQ,
                                    qb, nullptr, 1, qscale);
  gemm_qkvo<<<gg, 256, 0, stream>>>((const short*)xkb, (const short*)wkt, bK,
                                    kb, nullptr, 1, 1.0f);
  gemm_qkvo<<<gg, 256, 0, stream>>>((const short*)xvb, (const short*)wvt, bV,
                                    vtb, nullptr, 2, 1.0f);
  attn<<<1024, 256, 0, stream>>>((const short*)qb, (const short*)kb,
                                 (const short*)vtb, zb);
  gemm_qkvo<<<gg, 256, 0, stream>>>((const short*)zb, (const short*)wot, bO,
                                    nullptr, out, 0, 1.0f);
}